// Round 11
// baseline (348.780 us; speedup 1.0000x reference)
//
#include <hip/hip_runtime.h>
#include <hip/hip_bf16.h>

typedef short s16x8 __attribute__((ext_vector_type(8)));
typedef float f32x4 __attribute__((ext_vector_type(4)));
typedef unsigned short u16x8 __attribute__((ext_vector_type(8)));
typedef unsigned int u32x2 __attribute__((ext_vector_type(2)));

static constexpr int Bc   = 8;
static constexpr int Nn   = 24576;
static constexpr int Kk   = 16;
static constexpr int Cc   = 64;
static constexpr int Rr   = Bc * Nn;     // 196608
static constexpr float EPS = 1e-5f;

__device__ __forceinline__ unsigned short f2bf(float f) {
    union { float f; unsigned int u; } c; c.f = f;
    unsigned int r = c.u + 0x7FFFu + ((c.u >> 16) & 1u);  // RNE
    return (unsigned short)(r >> 16);
}
__device__ __forceinline__ float bf2f(unsigned short u) {
    union { unsigned int u; float f; } c; c.u = ((unsigned int)u) << 16; return c.f;
}
__device__ __forceinline__ float bflo(unsigned g) {
    union { unsigned u; float f; } c; c.u = g << 16; return c.f;
}
__device__ __forceinline__ float bfhi(unsigned g) {
    union { unsigned u; float f; } c; c.u = g & 0xffff0000u; return c.f;
}
__device__ __forceinline__ unsigned packbf(float lo, float hi) {
    return (unsigned)f2bf(lo) | ((unsigned)f2bf(hi) << 16);
}

// ---------------------------------------------------------------------------
// K1: h = x · W^T via MFMA (bf16 in, fp32 acc, bf16 out).
// XCD-batch partition: batch = bid%8. Block 0 zeroes the stats accumulator.
// ---------------------------------------------------------------------------
__global__ __launch_bounds__(256) void linear_mfma_kernel(
    const float* __restrict__ x, const float* __restrict__ W,
    __hip_bfloat16* __restrict__ h, float* __restrict__ stats)
{
    if (blockIdx.x == 0 && threadIdx.x < 128) stats[threadIdx.x] = 0.f;

    const int tid  = threadIdx.x;
    const int l    = tid & 63;
    const int wave = tid >> 6;
    const int batch = blockIdx.x & 7;          // -> XCD (round-robin dispatch)
    const int qb    = blockIdx.x >> 3;         // 0..255
    const int wib   = qb * 4 + wave;           // wave-in-batch 0..1023

    const int lr = l & 15;
    const int kg = (l >> 4) * 8;
    const int dr = (l >> 4) * 4;

    s16x8 bfrag[4][2];
#pragma unroll
    for (int ct = 0; ct < 4; ++ct)
#pragma unroll
        for (int kc = 0; kc < 2; ++kc) {
            const float* bp = W + (ct * 16 + lr) * 64 + kc * 32 + kg;
            f32x4 b0 = *reinterpret_cast<const f32x4*>(bp);
            f32x4 b1 = *reinterpret_cast<const f32x4*>(bp + 4);
            s16x8 f;
            f[0] = (short)f2bf(b0[0]); f[1] = (short)f2bf(b0[1]);
            f[2] = (short)f2bf(b0[2]); f[3] = (short)f2bf(b0[3]);
            f[4] = (short)f2bf(b1[0]); f[5] = (short)f2bf(b1[1]);
            f[6] = (short)f2bf(b1[2]); f[7] = (short)f2bf(b1[3]);
            bfrag[ct][kc] = f;
        }

    unsigned short* hu = (unsigned short*)h;
    const int tiles_per_batch = Nn / 16;       // 1536
    for (int t = wib; t < tiles_per_batch; t += 1024) {
        const int row0 = batch * Nn + t * 16;
        const float* ap = x + (size_t)(row0 + lr) * 64 + kg;
        f32x4 a0 = *reinterpret_cast<const f32x4*>(ap);
        f32x4 a1 = *reinterpret_cast<const f32x4*>(ap + 4);
        f32x4 a2 = *reinterpret_cast<const f32x4*>(ap + 32);
        f32x4 a3 = *reinterpret_cast<const f32x4*>(ap + 36);
        s16x8 fa0, fa1;
        fa0[0] = (short)f2bf(a0[0]); fa0[1] = (short)f2bf(a0[1]);
        fa0[2] = (short)f2bf(a0[2]); fa0[3] = (short)f2bf(a0[3]);
        fa0[4] = (short)f2bf(a1[0]); fa0[5] = (short)f2bf(a1[1]);
        fa0[6] = (short)f2bf(a1[2]); fa0[7] = (short)f2bf(a1[3]);
        fa1[0] = (short)f2bf(a2[0]); fa1[1] = (short)f2bf(a2[1]);
        fa1[2] = (short)f2bf(a2[2]); fa1[3] = (short)f2bf(a2[3]);
        fa1[4] = (short)f2bf(a3[0]); fa1[5] = (short)f2bf(a3[1]);
        fa1[6] = (short)f2bf(a3[2]); fa1[7] = (short)f2bf(a3[3]);

        f32x4 acc[4];
#pragma unroll
        for (int ct = 0; ct < 4; ++ct) { acc[ct] = (f32x4){0.f, 0.f, 0.f, 0.f}; }
#pragma unroll
        for (int ct = 0; ct < 4; ++ct) {
            acc[ct] = __builtin_amdgcn_mfma_f32_16x16x32_bf16(fa0, bfrag[ct][0], acc[ct], 0, 0, 0);
            acc[ct] = __builtin_amdgcn_mfma_f32_16x16x32_bf16(fa1, bfrag[ct][1], acc[ct], 0, 0, 0);
        }
#pragma unroll
        for (int ct = 0; ct < 4; ++ct)
#pragma unroll
            for (int r = 0; r < 4; ++r)
                hu[(size_t)(row0 + dr + r) * 64 + ct * 16 + lr] = f2bf(acc[ct][r]);
    }
}

// ---------------------------------------------------------------------------
// K2: v[r][o] = (max_k h[nbr(r,k)][o]) - h[r][o], bf16 in/out.
// 4 rows per gather INSTRUCTION: lane-group g = lane>>4 -> row, cl = lane&15
// -> channel quad (dwordx2 = 4 bf16). Cuts gather instr count 4x (TCP
// miss-pipeline hypothesis). knn loads: 2 coalesced full-wave dwords per
// 8 rows (layout lane = row_off*16+k); row index per lane-group via
// readlane(constant) + 3 cndmask. Own-h loads and v stores are contiguous
// scalar-base dwordx2 (byte off = lane*8). batch = bid%8 keeps the 3 MB h
// slice in the owning XCD's L2.
// ---------------------------------------------------------------------------
__global__ __launch_bounds__(256) void gather_bn_kernel(
    const __hip_bfloat16* __restrict__ h, const int* __restrict__ knn,
    __hip_bfloat16* __restrict__ v, float* __restrict__ stats)
{
    const int tid   = threadIdx.x;
    const int lane  = tid & 63;
    const int wave  = tid >> 6;
    const int batch = blockIdx.x & 7;
    const int qb    = blockIdx.x >> 3;
    const int wib   = qb * 4 + wave;           // 0..1023

    const unsigned* hu32 = (const unsigned*)h;
    unsigned* vu32 = (unsigned*)v;
    const int bbase = batch * Nn;

    const int g  = lane >> 4;                  // row within quad
    const int cl = lane & 15;                  // channel-quad index
    const int c0 = cl * 4;

    float sum[4] = {0.f, 0.f, 0.f, 0.f};
    float sq[4]  = {0.f, 0.f, 0.f, 0.f};

    const int rbase = bbase + wib * 24;        // 24 rows per wave
#pragma unroll 1
    for (int it = 0; it < 3; ++it) {
        const int r0 = rbase + it * 8;
        // indices for 8 rows: 128 ints contiguous; lane = row_off*16 + k
        const int iA = knn[(size_t)r0 * Kk + lane];        // rows r0..r0+3
        const int iB = knn[(size_t)r0 * Kk + 64 + lane];   // rows r0+4..r0+7
        // own h: rows r0..r0+3 / r0+4..r0+7, contiguous (lane*8 bytes)
        const u32x2 oA = *reinterpret_cast<const u32x2*>(hu32 + (size_t)r0 * 32 + lane * 2);
        const u32x2 oB = *reinterpret_cast<const u32x2*>(hu32 + (size_t)r0 * 32 + 128 + lane * 2);

        float mA0 = -3e38f, mA1 = -3e38f, mA2 = -3e38f, mA3 = -3e38f;
        float mB0 = -3e38f, mB1 = -3e38f, mB2 = -3e38f, mB3 = -3e38f;
#pragma unroll
        for (int k = 0; k < Kk; ++k) {
            const int a0 = __builtin_amdgcn_readlane(iA, k);
            const int a1 = __builtin_amdgcn_readlane(iA, 16 + k);
            const int a2 = __builtin_amdgcn_readlane(iA, 32 + k);
            const int a3 = __builtin_amdgcn_readlane(iA, 48 + k);
            const int b0 = __builtin_amdgcn_readlane(iB, k);
            const int b1 = __builtin_amdgcn_readlane(iB, 16 + k);
            const int b2 = __builtin_amdgcn_readlane(iB, 32 + k);
            const int b3 = __builtin_amdgcn_readlane(iB, 48 + k);
            const int tA0 = (g & 1) ? a1 : a0;
            const int tA1 = (g & 1) ? a3 : a2;
            const int jA  = (g & 2) ? tA1 : tA0;
            const int tB0 = (g & 1) ? b1 : b0;
            const int tB1 = (g & 1) ? b3 : b2;
            const int jB  = (g & 2) ? tB1 : tB0;
            const u32x2 ga = *reinterpret_cast<const u32x2*>(hu32 + (size_t)(bbase + jA) * 32 + cl * 2);
            const u32x2 gb = *reinterpret_cast<const u32x2*>(hu32 + (size_t)(bbase + jB) * 32 + cl * 2);
            mA0 = fmaxf(mA0, bflo(ga[0])); mA1 = fmaxf(mA1, bfhi(ga[0]));
            mA2 = fmaxf(mA2, bflo(ga[1])); mA3 = fmaxf(mA3, bfhi(ga[1]));
            mB0 = fmaxf(mB0, bflo(gb[0])); mB1 = fmaxf(mB1, bfhi(gb[0]));
            mB2 = fmaxf(mB2, bflo(gb[1])); mB3 = fmaxf(mB3, bfhi(gb[1]));
        }
        const float vA0 = mA0 - bflo(oA[0]);
        const float vA1 = mA1 - bfhi(oA[0]);
        const float vA2 = mA2 - bflo(oA[1]);
        const float vA3 = mA3 - bfhi(oA[1]);
        const float vB0 = mB0 - bflo(oB[0]);
        const float vB1 = mB1 - bfhi(oB[0]);
        const float vB2 = mB2 - bflo(oB[1]);
        const float vB3 = mB3 - bfhi(oB[1]);

        u32x2 sA, sB;
        sA[0] = packbf(vA0, vA1); sA[1] = packbf(vA2, vA3);
        sB[0] = packbf(vB0, vB1); sB[1] = packbf(vB2, vB3);
        *reinterpret_cast<u32x2*>(vu32 + (size_t)r0 * 32 + lane * 2) = sA;
        *reinterpret_cast<u32x2*>(vu32 + (size_t)r0 * 32 + 128 + lane * 2) = sB;

        sum[0] += vA0 + vB0; sum[1] += vA1 + vB1;
        sum[2] += vA2 + vB2; sum[3] += vA3 + vB3;
        sq[0]  += vA0 * vA0 + vB0 * vB0; sq[1] += vA1 * vA1 + vB1 * vB1;
        sq[2]  += vA2 * vA2 + vB2 * vB2; sq[3] += vA3 * vA3 + vB3 * vB3;
    }

    // reduce across the 4 lane-groups (same cl -> same channels)
    float st[8] = {sum[0], sum[1], sum[2], sum[3], sq[0], sq[1], sq[2], sq[3]};
#pragma unroll
    for (int j = 0; j < 8; ++j) {
        st[j] += __shfl_xor(st[j], 16);
        st[j] += __shfl_xor(st[j], 32);
    }

    __shared__ float sred[4][16][8];
    if (g == 0) {
#pragma unroll
        for (int j = 0; j < 8; ++j) sred[wave][cl][j] = st[j];
    }
    __syncthreads();
    if (wave == 0 && g == 0) {
#pragma unroll
        for (int j = 0; j < 8; ++j) {
            const float t = sred[0][cl][j] + sred[1][cl][j] + sred[2][cl][j] + sred[3][cl][j];
            if (j < 4) atomicAdd(&stats[c0 + j], t);
            else       atomicAdd(&stats[64 + c0 + (j - 4)], t);
        }
    }
}

// ---------------------------------------------------------------------------
// K3: out = v_bf16 * scale[c] + shift[c]. scale/shift computed per-block
// from stats. Same batch partition: v read from the XCD L2 K2 wrote through.
// ---------------------------------------------------------------------------
__global__ __launch_bounds__(256) void norm_kernel(
    const __hip_bfloat16* __restrict__ v, const float* __restrict__ stats,
    const float* __restrict__ gamma, const float* __restrict__ beta,
    float* __restrict__ out)
{
    __shared__ float sc[64], sh[64];
    if (threadIdx.x < 64) {
        const int o = threadIdx.x;
        const float inv = 1.0f / (float)Rr;
        const float mean = stats[o] * inv;
        const float var  = stats[64 + o] * inv - mean * mean;
        const float s    = gamma[o] * rsqrtf(var + EPS);
        sc[o] = s;
        sh[o] = beta[o] - mean * s;
    }
    __syncthreads();

    const int batch = blockIdx.x & 7;
    const int qb    = blockIdx.x >> 3;          // 0..255
    const u16x8* vu = (const u16x8*)v;
    const int per_batch8 = Nn * 64 / 8;         // groups of 8 elems per batch
    const size_t base8 = (size_t)batch * per_batch8;

    for (int li = qb * 256 + threadIdx.x; li < per_batch8; li += 256 * 256) {
        const size_t i = base8 + li;
        u16x8 t = vu[i];
        const int c = (li * 8) & 63;
        f32x4 r0, r1;
        r0[0] = bf2f(t[0]) * sc[c + 0] + sh[c + 0];
        r0[1] = bf2f(t[1]) * sc[c + 1] + sh[c + 1];
        r0[2] = bf2f(t[2]) * sc[c + 2] + sh[c + 2];
        r0[3] = bf2f(t[3]) * sc[c + 3] + sh[c + 3];
        r1[0] = bf2f(t[4]) * sc[c + 4] + sh[c + 4];
        r1[1] = bf2f(t[5]) * sc[c + 5] + sh[c + 5];
        r1[2] = bf2f(t[6]) * sc[c + 6] + sh[c + 6];
        r1[3] = bf2f(t[7]) * sc[c + 7] + sh[c + 7];
        f32x4* op = reinterpret_cast<f32x4*>(out + i * 8);
        __builtin_nontemporal_store(r0, op);
        __builtin_nontemporal_store(r1, op + 1);
    }
}

// ---------------------------------------------------------------------------
extern "C" void kernel_launch(void* const* d_in, const int* in_sizes, int n_in,
                              void* d_out, int out_size, void* d_ws, size_t ws_size,
                              hipStream_t stream)
{
    const float* x     = (const float*)d_in[0];
    const float* W     = (const float*)d_in[1];
    const float* gamma = (const float*)d_in[2];
    const float* beta  = (const float*)d_in[3];
    const int*   knn   = (const int*)d_in[4];
    float*       out   = (float*)d_out;

    // ws layout: h bf16 [Rr*64] | v bf16 [Rr*64] | stats[128]
    __hip_bfloat16* h = (__hip_bfloat16*)d_ws;
    __hip_bfloat16* v = h + (size_t)Rr * 64;
    float* stats = (float*)((char*)d_ws + 2 * (size_t)Rr * 64 * sizeof(__hip_bfloat16));

    linear_mfma_kernel<<<2048, 256, 0, stream>>>(x, W, h, stats);
    gather_bn_kernel<<<2048, 256, 0, stream>>>(h, knn, v, stats);
    norm_kernel<<<2048, 256, 0, stream>>>(v, stats, gamma, beta, out);
}